// Round 1
// baseline (266.402 us; speedup 1.0000x reference)
//
#include <hip/hip_runtime.h>
#include <hip/hip_bf16.h>
#include <stdint.h>

typedef unsigned short u16;
typedef unsigned int   u32;
typedef short bf16x8 __attribute__((ext_vector_type(8)));
typedef float f32x4  __attribute__((ext_vector_type(4)));

#define MFMA16(A,B,C) __builtin_amdgcn_mfma_f32_16x16x32_bf16((A),(B),(C),0,0,0)

// fp32 -> bf16 round-to-nearest-even
__device__ __forceinline__ u16 f2b(float x) {
  u32 u = __float_as_uint(x);
  u += 0x7fffu + ((u >> 16) & 1u);
  return (u16)(u >> 16);
}
__device__ __forceinline__ u32 packbf(float lo, float hi) {
  return (u32)f2b(lo) | ((u32)f2b(hi) << 16);
}

typedef __attribute__((address_space(1))) const void glob_void;
typedef __attribute__((address_space(3))) void lds_void;
__device__ __forceinline__ void gld16(const void* g, void* s) {
  __builtin_amdgcn_global_load_lds((glob_void*)g, (lds_void*)s, 16, 0, 0);
}

// ---------------------------------------------------------------- convert
__global__ void cvt_bf16(const float4* __restrict__ in, ushort4* __restrict__ out, int n4) {
  int stride = gridDim.x * blockDim.x;
  for (int i = blockIdx.x * blockDim.x + threadIdx.x; i < n4; i += stride) {
    float4 v = in[i];
    ushort4 o;
    o.x = f2b(v.x); o.y = f2b(v.y); o.z = f2b(v.z); o.w = f2b(v.w);
    out[i] = o;
  }
}

// ---------------------------------------------------------------- QKV GEMM
// C[m,o] = sum_k x[m,k] * w[o,k]; m in [0,16384), o in [0,2304), k in [0,768)
// Epilogue scatters into q/k (b,h,n,d) and vt (b,h,d,n), q pre-scaled by SCALE*log2e.
__global__ __launch_bounds__(256) void gemm_qkv(
    const u16* __restrict__ xb, const u16* __restrict__ wb,
    u16* __restrict__ q, u16* __restrict__ k, u16* __restrict__ vt)
{
  __shared__ u16 lA[128*32];
  __shared__ u16 lB[128*32];
  const int tid = threadIdx.x;
  const int lane = tid & 63;
  const int wv = tid >> 6;
  const int wr = wv >> 1, wc = wv & 1;
  const int m0 = blockIdx.x << 7;
  const int o0 = blockIdx.y << 7;
  f32x4 acc[4][4] = {};
  const int srow = tid >> 2;
  const int sb   = (tid & 3) << 4;
  const char* gA0 = (const char*)(xb + (size_t)(m0 + srow)      * 768) + sb;
  const char* gA1 = (const char*)(xb + (size_t)(m0 + 64 + srow) * 768) + sb;
  const char* gB0 = (const char*)(wb + (size_t)(o0 + srow)      * 768) + sb;
  const char* gB1 = (const char*)(wb + (size_t)(o0 + 64 + srow) * 768) + sb;
  char* sA = (char*)lA + tid * 16;
  char* sB = (char*)lB + tid * 16;
  const int frow = lane & 15;
  const int fk   = (lane >> 4) << 4;  // byte offset of 8-elem k-chunk in 64B row
  for (int kt = 0; kt < 24; ++kt) {
    const int kb = kt << 6;
    gld16(gA0 + kb, sA);
    gld16(gA1 + kb, sA + 4096);
    gld16(gB0 + kb, sB);
    gld16(gB1 + kb, sB + 4096);
    asm volatile("s_waitcnt vmcnt(0)" ::: "memory");
    __syncthreads();
    bf16x8 af[4], bfr[4];
#pragma unroll
    for (int m = 0; m < 4; ++m)
      af[m] = *(const bf16x8*)((const char*)lA + ((wr*64 + m*16 + frow) << 6) + fk);
#pragma unroll
    for (int n = 0; n < 4; ++n)
      bfr[n] = *(const bf16x8*)((const char*)lB + ((wc*64 + n*16 + frow) << 6) + fk);
#pragma unroll
    for (int m = 0; m < 4; ++m)
#pragma unroll
      for (int n = 0; n < 4; ++n)
        acc[m][n] = MFMA16(af[m], bfr[n], acc[m][n]);
    __syncthreads();
  }
  const int which = o0 / 768;           // uniform per block (128 | 768 boundaries)
  const int ob = o0 - which * 768;
  const float QSCALE = 0.18033688011112042f; // 0.125 * log2(e)
#pragma unroll
  for (int n = 0; n < 4; ++n) {
    const int go = ob + wc*64 + n*16 + (lane & 15);
    const int h = go >> 6, d = go & 63;
#pragma unroll
    for (int m = 0; m < 4; ++m) {
#pragma unroll
      for (int r = 0; r < 4; ++r) {
        const int gm = m0 + wr*64 + m*16 + ((lane >> 4) << 2) + r;
        const int b = gm >> 10, nn = gm & 1023;
        const float v = acc[m][n][r];
        if (which == 0)      q [((size_t)((b*12 + h)*1024 + nn) << 6) + d]  = f2b(v * QSCALE);
        else if (which == 1) k [((size_t)((b*12 + h)*1024 + nn) << 6) + d]  = f2b(v);
        else                 vt[((size_t)((b*12 + h)*64 + d)   << 10) + nn] = f2b(v);
      }
    }
  }
}

// ---------------------------------------------------------------- attention
// q pre-scaled by SCALE*log2e; softmax in base 2. One block = 64 q-rows of one
// (b,h); 4 waves x 16 rows. KVBLK=64 staged to LDS, XOR-swizzled (16B chunks
// within 128B rows) via pre-swizzled global source (both-sides involution).
__global__ __launch_bounds__(256) void attn_fwd(
    const u16* __restrict__ q, const u16* __restrict__ kk,
    const u16* __restrict__ vt, u16* __restrict__ ao)
{
  __shared__ u16 lK[64*64];
  __shared__ u16 lV[64*64];
  const int tid = threadIdx.x, lane = tid & 63, wv = tid >> 6;
  const int qt = blockIdx.x, bh = blockIdx.y;
  const u16*  qb = q  + ((size_t)bh << 16);
  const char* kg = (const char*)(kk + ((size_t)bh << 16));
  const char* vg = (const char*)(vt + ((size_t)bh << 16));
  const int qc = lane & 15, kgp = lane >> 4;
  const int qrow = (qt << 6) + (wv << 4) + qc;
  const bf16x8 qf0 = *(const bf16x8*)(qb + (size_t)qrow*64      + (kgp << 3));
  const bf16x8 qf1 = *(const bf16x8*)(qb + (size_t)qrow*64 + 32 + (kgp << 3));
  f32x4 ot[4] = {};
  float mrun = -1e30f, lrun = 0.f;
  // staging offsets (per thread, 2 x 16B per tile per array)
  const int o1 = tid << 4, o2 = o1 + 4096;
  const int ko1 = o1 ^ (((o1 >> 7) & 7) << 4);
  const int ko2 = o2 ^ (((o2 >> 7) & 7) << 4);
  const int d1 = o1 >> 7, d2 = o2 >> 7;
  const int vo1 = d1*2048 + ((o1 & 127) ^ ((d1 & 7) << 4));
  const int vo2 = d2*2048 + ((o2 & 127) ^ ((d2 & 7) << 4));
  char* sK = (char*)lK;
  char* sV = (char*)lV;
  for (int t0 = 0; t0 < 16; ++t0) {
    gld16(kg + (t0 << 13) + ko1, sK + o1);
    gld16(kg + (t0 << 13) + ko2, sK + o2);
    gld16(vg + (t0 << 7) + vo1, sV + o1);
    gld16(vg + (t0 << 7) + vo2, sV + o2);
    asm volatile("s_waitcnt vmcnt(0)" ::: "memory");
    __syncthreads();
    // S^T tiles: p[g] holds S^T[kv=16g+4*kgp+r][q=qc]  (C layout, m89-verified)
    f32x4 p[4];
#pragma unroll
    for (int g = 0; g < 4; ++g) {
      const int row = (g << 4) + qc;
      const int rb = row << 7;
      const int sw = (row & 7) << 4;
      bf16x8 kf0 = *(const bf16x8*)(sK + rb + (((kgp << 4)     ) ^ sw));
      bf16x8 kf1 = *(const bf16x8*)(sK + rb + (((kgp << 4) + 64) ^ sw));
      f32x4 s = {0.f, 0.f, 0.f, 0.f};
      s = MFMA16(kf0, qf0, s);
      s = MFMA16(kf1, qf1, s);
      p[g] = s;
    }
    // online softmax over this 64-kv tile (per q-column = per lane&15)
    float mloc = p[0][0];
#pragma unroll
    for (int g = 0; g < 4; ++g)
#pragma unroll
      for (int r = 0; r < 4; ++r) mloc = fmaxf(mloc, p[g][r]);
    mloc = fmaxf(mloc, __shfl_xor(mloc, 16));
    mloc = fmaxf(mloc, __shfl_xor(mloc, 32));
    const float mnew  = fmaxf(mrun, mloc);
    const float alpha = __builtin_amdgcn_exp2f(mrun - mnew);
    float sum = 0.f;
#pragma unroll
    for (int g = 0; g < 4; ++g)
#pragma unroll
      for (int r = 0; r < 4; ++r) {
        p[g][r] = __builtin_amdgcn_exp2f(p[g][r] - mnew);
        sum += p[g][r];
      }
    sum += __shfl_xor(sum, 16);
    sum += __shfl_xor(sum, 32);
    lrun = lrun * alpha + sum;
    mrun = mnew;
#pragma unroll
    for (int db = 0; db < 4; ++db) ot[db] *= alpha;
    // re-layout P into PV B-operand frags (lane(kgp,qc) elem j <-> kv=32hh+8kgp+j)
    u32 pk0[2], pk1[2], pk2[2], pk3[2];
    pk0[0]=packbf(p[0][0],p[0][1]); pk0[1]=packbf(p[0][2],p[0][3]);
    pk1[0]=packbf(p[1][0],p[1][1]); pk1[1]=packbf(p[1][2],p[1][3]);
    pk2[0]=packbf(p[2][0],p[2][1]); pk2[1]=packbf(p[2][2],p[2][3]);
    pk3[0]=packbf(p[3][0],p[3][1]); pk3[1]=packbf(p[3][2],p[3][3]);
    union { u32 u[4]; bf16x8 v; } pt0, pt1;
#pragma unroll
    for (int j2 = 0; j2 < 4; ++j2) {
      const int lg  = (2*kgp + (j2 >> 1)) & 3;
      const int src = (lg << 4) | qc;
      u32 a0 = __shfl(pk0[j2 & 1], src);
      u32 b0 = __shfl(pk1[j2 & 1], src);
      pt0.u[j2] = (kgp >= 2) ? b0 : a0;
      u32 a1 = __shfl(pk2[j2 & 1], src);
      u32 b1 = __shfl(pk3[j2 & 1], src);
      pt1.u[j2] = (kgp >= 2) ? b1 : a1;
    }
    // O^T[d][q] += VT[d][kv] * P; A = VT frag (contiguous kv), B = pt
#pragma unroll
    for (int db = 0; db < 4; ++db) {
      const int row = (db << 4) + qc;   // d within 64
      const int rb = row << 7;
      const int sw = (row & 7) << 4;
      bf16x8 vf0 = *(const bf16x8*)(sV + rb + (((kgp << 4)     ) ^ sw));
      bf16x8 vf1 = *(const bf16x8*)(sV + rb + (((kgp << 4) + 64) ^ sw));
      ot[db] = MFMA16(vf0, pt0.v, ot[db]);
      ot[db] = MFMA16(vf1, pt1.v, ot[db]);
    }
    __syncthreads();
  }
  const float linv = 1.f / lrun;
  const int b = bh / 12, h = bh % 12;
  const size_t base = ((size_t)((b << 10) + qrow) * 768) + (h << 6) + (kgp << 2);
#pragma unroll
  for (int db = 0; db < 4; ++db) {
    ushort4 o4;
    o4.x = f2b(ot[db][0] * linv);
    o4.y = f2b(ot[db][1] * linv);
    o4.z = f2b(ot[db][2] * linv);
    o4.w = f2b(ot[db][3] * linv);
    *(ushort4*)(ao + base + (db << 4)) = o4;
  }
}

// ---------------------------------------------------------------- proj GEMM
__global__ __launch_bounds__(256) void gemm_proj(
    const u16* __restrict__ ab, const u16* __restrict__ wb,
    const float* __restrict__ bias, float* __restrict__ out)
{
  __shared__ u16 lA[128*32];
  __shared__ u16 lB[128*32];
  const int tid = threadIdx.x;
  const int lane = tid & 63;
  const int wv = tid >> 6;
  const int wr = wv >> 1, wc = wv & 1;
  const int m0 = blockIdx.x << 7;
  const int o0 = blockIdx.y << 7;
  f32x4 acc[4][4] = {};
  const int srow = tid >> 2;
  const int sb   = (tid & 3) << 4;
  const char* gA0 = (const char*)(ab + (size_t)(m0 + srow)      * 768) + sb;
  const char* gA1 = (const char*)(ab + (size_t)(m0 + 64 + srow) * 768) + sb;
  const char* gB0 = (const char*)(wb + (size_t)(o0 + srow)      * 768) + sb;
  const char* gB1 = (const char*)(wb + (size_t)(o0 + 64 + srow) * 768) + sb;
  char* sA = (char*)lA + tid * 16;
  char* sB = (char*)lB + tid * 16;
  const int frow = lane & 15;
  const int fk   = (lane >> 4) << 4;
  for (int kt = 0; kt < 24; ++kt) {
    const int kb = kt << 6;
    gld16(gA0 + kb, sA);
    gld16(gA1 + kb, sA + 4096);
    gld16(gB0 + kb, sB);
    gld16(gB1 + kb, sB + 4096);
    asm volatile("s_waitcnt vmcnt(0)" ::: "memory");
    __syncthreads();
    bf16x8 af[4], bfr[4];
#pragma unroll
    for (int m = 0; m < 4; ++m)
      af[m] = *(const bf16x8*)((const char*)lA + ((wr*64 + m*16 + frow) << 6) + fk);
#pragma unroll
    for (int n = 0; n < 4; ++n)
      bfr[n] = *(const bf16x8*)((const char*)lB + ((wc*64 + n*16 + frow) << 6) + fk);
#pragma unroll
    for (int m = 0; m < 4; ++m)
#pragma unroll
      for (int n = 0; n < 4; ++n)
        acc[m][n] = MFMA16(af[m], bfr[n], acc[m][n]);
    __syncthreads();
  }
#pragma unroll
  for (int n = 0; n < 4; ++n) {
    const int go = o0 + wc*64 + n*16 + (lane & 15);
    const float bv = bias[go];
#pragma unroll
    for (int m = 0; m < 4; ++m) {
#pragma unroll
      for (int r = 0; r < 4; ++r) {
        const int gm = m0 + wr*64 + m*16 + ((lane >> 4) << 2) + r;
        out[(size_t)gm * 768 + go] = acc[m][n][r] + bv;
      }
    }
  }
}

// ---------------------------------------------------------------- launch
extern "C" void kernel_launch(void* const* d_in, const int* in_sizes, int n_in,
                              void* d_out, int out_size, void* d_ws, size_t ws_size,
                              hipStream_t stream)
{
  (void)in_sizes; (void)n_in; (void)out_size; (void)ws_size;
  const float* x  = (const float*)d_in[0];
  const float* wq = (const float*)d_in[1];
  const float* wp = (const float*)d_in[2];
  const float* bp = (const float*)d_in[3];
  float* out = (float*)d_out;
  char* ws = (char*)d_ws;
  // workspace layout (bytes)
  u16* xb     = (u16*)(ws);              // 25,165,824  x bf16 [16384][768]
  u16* wqkvb  = (u16*)(ws + 25165824);   //  3,538,944  w_qkv bf16
  u16* wprojb = (u16*)(ws + 28704768);   //  1,179,648  w_proj bf16
  u16* qa     = (u16*)(ws + 29884416);   // 25,165,824  q  [192][1024][64] (pre-scaled)
  u16* ka     = (u16*)(ws + 55050240);   // 25,165,824  k  [192][1024][64]
  u16* vta    = (u16*)(ws + 80216064);   // 25,165,824  v^T[192][64][1024]
  u16* ao     = xb;                      // alias: xb dead after gemm_qkv

  cvt_bf16<<<2048, 256, 0, stream>>>((const float4*)x,  (ushort4*)xb,     3145728);
  cvt_bf16<<<1024, 256, 0, stream>>>((const float4*)wq, (ushort4*)wqkvb,   442368);
  cvt_bf16<<< 576, 256, 0, stream>>>((const float4*)wp, (ushort4*)wprojb,  147456);
  gemm_qkv<<<dim3(128, 18), 256, 0, stream>>>(xb, wqkvb, qa, ka, vta);
  attn_fwd<<<dim3(16, 192), 256, 0, stream>>>(qa, ka, vta, ao);
  gemm_proj<<<dim3(128, 6), 256, 0, stream>>>(ao, wprojb, bp, out);
}

// Round 2
// 242.647 us; speedup vs baseline: 1.0979x; 1.0979x over previous
//
#include <hip/hip_runtime.h>
#include <hip/hip_bf16.h>
#include <stdint.h>

typedef unsigned short u16;
typedef unsigned int   u32;
typedef short bf16x8 __attribute__((ext_vector_type(8)));
typedef float f32x4  __attribute__((ext_vector_type(4)));
typedef float f32x16 __attribute__((ext_vector_type(16)));

#define MFMA16(A,B,C) __builtin_amdgcn_mfma_f32_16x16x32_bf16((A),(B),(C),0,0,0)
#define MFMA32(A,B,C) __builtin_amdgcn_mfma_f32_32x32x16_bf16((A),(B),(C),0,0,0)

// fp32 -> bf16 round-to-nearest-even
__device__ __forceinline__ u16 f2b(float x) {
  u32 u = __float_as_uint(x);
  u += 0x7fffu + ((u >> 16) & 1u);
  return (u16)(u >> 16);
}
// packed f32 pair -> bf16x2 (hardware RNE pack)
__device__ __forceinline__ u32 cvtpk(float lo, float hi) {
  u32 r;
  asm("v_cvt_pk_bf16_f32 %0, %1, %2" : "=v"(r) : "v"(lo), "v"(hi));
  return r;
}

typedef __attribute__((address_space(1))) const void glob_void;
typedef __attribute__((address_space(3))) void lds_void;
__device__ __forceinline__ void gld16(const void* g, void* s) {
  __builtin_amdgcn_global_load_lds((glob_void*)g, (lds_void*)s, 16, 0, 0);
}

// ---------------------------------------------------------------- convert
__global__ void cvt_bf16(const float4* __restrict__ in, ushort4* __restrict__ out, int n4) {
  int stride = gridDim.x * blockDim.x;
  for (int i = blockIdx.x * blockDim.x + threadIdx.x; i < n4; i += stride) {
    float4 v = in[i];
    ushort4 o;
    o.x = f2b(v.x); o.y = f2b(v.y); o.z = f2b(v.z); o.w = f2b(v.w);
    out[i] = o;
  }
}

// ---------------------------------------------------------------- QKV GEMM
__global__ __launch_bounds__(256) void gemm_qkv(
    const u16* __restrict__ xb, const u16* __restrict__ wb,
    u16* __restrict__ q, u16* __restrict__ k, u16* __restrict__ vt)
{
  __shared__ u16 lA[128*32];
  __shared__ u16 lB[128*32];
  const int tid = threadIdx.x;
  const int lane = tid & 63;
  const int wv = tid >> 6;
  const int wr = wv >> 1, wc = wv & 1;
  const int m0 = blockIdx.x << 7;
  const int o0 = blockIdx.y << 7;
  f32x4 acc[4][4] = {};
  const int srow = tid >> 2;
  const int sb   = (tid & 3) << 4;
  const char* gA0 = (const char*)(xb + (size_t)(m0 + srow)      * 768) + sb;
  const char* gA1 = (const char*)(xb + (size_t)(m0 + 64 + srow) * 768) + sb;
  const char* gB0 = (const char*)(wb + (size_t)(o0 + srow)      * 768) + sb;
  const char* gB1 = (const char*)(wb + (size_t)(o0 + 64 + srow) * 768) + sb;
  char* sA = (char*)lA + tid * 16;
  char* sB = (char*)lB + tid * 16;
  const int frow = lane & 15;
  const int fk   = (lane >> 4) << 4;
  for (int kt = 0; kt < 24; ++kt) {
    const int kb = kt << 6;
    gld16(gA0 + kb, sA);
    gld16(gA1 + kb, sA + 4096);
    gld16(gB0 + kb, sB);
    gld16(gB1 + kb, sB + 4096);
    asm volatile("s_waitcnt vmcnt(0)" ::: "memory");
    __syncthreads();
    bf16x8 af[4], bfr[4];
#pragma unroll
    for (int m = 0; m < 4; ++m)
      af[m] = *(const bf16x8*)((const char*)lA + ((wr*64 + m*16 + frow) << 6) + fk);
#pragma unroll
    for (int n = 0; n < 4; ++n)
      bfr[n] = *(const bf16x8*)((const char*)lB + ((wc*64 + n*16 + frow) << 6) + fk);
#pragma unroll
    for (int m = 0; m < 4; ++m)
#pragma unroll
      for (int n = 0; n < 4; ++n)
        acc[m][n] = MFMA16(af[m], bfr[n], acc[m][n]);
    __syncthreads();
  }
  const int which = o0 / 768;
  const int ob = o0 - which * 768;
  const float QSCALE = 0.18033688011112042f; // 0.125 * log2(e)
#pragma unroll
  for (int n = 0; n < 4; ++n) {
    const int go = ob + wc*64 + n*16 + (lane & 15);
    const int h = go >> 6, d = go & 63;
#pragma unroll
    for (int m = 0; m < 4; ++m) {
#pragma unroll
      for (int r = 0; r < 4; ++r) {
        const int gm = m0 + wr*64 + m*16 + ((lane >> 4) << 2) + r;
        const int b = gm >> 10, nn = gm & 1023;
        const float v = acc[m][n][r];
        if (which == 0)      q [((size_t)((b*12 + h)*1024 + nn) << 6) + d]  = f2b(v * QSCALE);
        else if (which == 1) k [((size_t)((b*12 + h)*1024 + nn) << 6) + d]  = f2b(v);
        else                 vt[((size_t)((b*12 + h)*64 + d)   << 10) + nn] = f2b(v);
      }
    }
  }
}

// ---------------------------------------------------------------- attention
// 32x32 swapped-QK structure (m214-style): 4 waves x 32 q-rows = QBLK 128.
// q pre-scaled by SCALE*log2e; softmax in base 2. KVBLK=64 in LDS, rows
// XOR-swizzled (16B granules, row&7) via pre-swizzled global source.
// Lane holds S^T[kv][q=l&31] for 32 of 64 kv (row=(r&3)+8(r>>2)+4hh);
// P->PV B-operand via v_cvt_pk_bf16_f32 + v_permlane32_swap_b32 (T12).
__global__ __launch_bounds__(256) void attn_fwd(
    const u16* __restrict__ q, const u16* __restrict__ kk,
    const u16* __restrict__ vt, u16* __restrict__ ao)
{
  __shared__ u16 lK[64*64];
  __shared__ u16 lV[64*64];
  const int tid = threadIdx.x, lane = tid & 63, wv = tid >> 6;
  const int l31 = lane & 31, hh = lane >> 5;
  const int qt = blockIdx.x, bh = blockIdx.y;
  const u16*  qb = q  + ((size_t)bh << 16);
  const char* kg = (const char*)(kk + ((size_t)bh << 16));
  const char* vg = (const char*)(vt + ((size_t)bh << 16));
  const int qrow = (qt << 7) + (wv << 5) + l31;
  // Q regs = B-operand frags: qreg[c] elem j = Q[qrow][16c + 8hh + j]
  bf16x8 qreg[4];
#pragma unroll
  for (int c = 0; c < 4; ++c)
    qreg[c] = *(const bf16x8*)((const char*)qb + (size_t)qrow*128 + c*32 + hh*16);
  f32x16 ot[2] = {};
  float mrun = -1e30f, lrun = 0.f;
  // staging offsets (per thread, 2 x 16B per tile per array), both-sides swizzle
  const int o1 = tid << 4, o2 = o1 + 4096;
  const int ko1 = o1 ^ (((o1 >> 7) & 7) << 4);
  const int ko2 = o2 ^ (((o2 >> 7) & 7) << 4);
  const int d1 = o1 >> 7, d2 = o2 >> 7;
  const int vo1 = d1*2048 + ((o1 & 127) ^ ((d1 & 7) << 4));
  const int vo2 = d2*2048 + ((o2 & 127) ^ ((d2 & 7) << 4));
  char* sK = (char*)lK;
  char* sV = (char*)lV;
  for (int t0 = 0; t0 < 16; ++t0) {
    gld16(kg + (t0 << 13) + ko1, sK + o1);
    gld16(kg + (t0 << 13) + ko2, sK + o2);
    gld16(vg + (t0 << 7) + vo1, sV + o1);
    gld16(vg + (t0 << 7) + vo2, sV + o2);
    asm volatile("s_waitcnt vmcnt(0)" ::: "memory");
    __syncthreads();
    // QK^T: s[tt] = S^T tile (kv = 32tt + crow, q = l31)
    f32x16 s[2] = {};
#pragma unroll
    for (int tt = 0; tt < 2; ++tt) {
      const int row = (tt << 5) + l31;
      const int rb = row << 7;
      const int sw = (row & 7) << 4;
#pragma unroll
      for (int c = 0; c < 4; ++c) {
        bf16x8 kf = *(const bf16x8*)(sK + rb + (((c << 5) + (hh << 4)) ^ sw));
        s[tt] = MFMA32(kf, qreg[c], s[tt]);
      }
    }
    // online softmax: lane owns 32 of 64 kv for q=l31; partner is lane^32
    float mloc = s[0][0];
#pragma unroll
    for (int tt = 0; tt < 2; ++tt)
#pragma unroll
      for (int r = 0; r < 16; ++r) mloc = fmaxf(mloc, s[tt][r]);
    mloc = fmaxf(mloc, __shfl_xor(mloc, 32));
    const float mnew  = fmaxf(mrun, mloc);
    const float alpha = __builtin_amdgcn_exp2f(mrun - mnew);
    float sum = 0.f;
#pragma unroll
    for (int tt = 0; tt < 2; ++tt)
#pragma unroll
      for (int r = 0; r < 16; ++r) {
        s[tt][r] = __builtin_amdgcn_exp2f(s[tt][r] - mnew);
        sum += s[tt][r];
      }
    sum += __shfl_xor(sum, 32);
    lrun = lrun * alpha + sum;
    mrun = mnew;
#pragma unroll
    for (int dt = 0; dt < 2; ++dt)
#pragma unroll
      for (int r = 0; r < 16; ++r) ot[dt][r] *= alpha;
    // P -> PV B-frags: pb[cc] elem j = P^T[kv=16cc+8hh+j][q=l31]
    bf16x8 pb[4];
#pragma unroll
    for (int tt = 0; tt < 2; ++tt) {
      u32 x0 = cvtpk(s[tt][0],  s[tt][1]);
      u32 y0 = cvtpk(s[tt][4],  s[tt][5]);
      u32 x1 = cvtpk(s[tt][2],  s[tt][3]);
      u32 y1 = cvtpk(s[tt][6],  s[tt][7]);
      asm("v_permlane32_swap_b32 %0, %1" : "+v"(x0), "+v"(y0));
      asm("v_permlane32_swap_b32 %0, %1" : "+v"(x1), "+v"(y1));
      u32 x2 = cvtpk(s[tt][8],  s[tt][9]);
      u32 y2 = cvtpk(s[tt][12], s[tt][13]);
      u32 x3 = cvtpk(s[tt][10], s[tt][11]);
      u32 y3 = cvtpk(s[tt][14], s[tt][15]);
      asm("v_permlane32_swap_b32 %0, %1" : "+v"(x2), "+v"(y2));
      asm("v_permlane32_swap_b32 %0, %1" : "+v"(x3), "+v"(y3));
      union { u32 u[4]; bf16x8 v; } a, b;
      a.u[0] = x0; a.u[1] = x1; a.u[2] = y0; a.u[3] = y1;
      b.u[0] = x2; b.u[1] = x3; b.u[2] = y2; b.u[3] = y3;
      pb[2*tt]     = a.v;
      pb[2*tt + 1] = b.v;
    }
    // PV: O^T[d][q] += VT[d][kv] * P^T[kv][q]
#pragma unroll
    for (int dt = 0; dt < 2; ++dt) {
      const int row = (dt << 5) + l31;
      const int rb = row << 7;
      const int sw = (row & 7) << 4;
#pragma unroll
      for (int cc = 0; cc < 4; ++cc) {
        bf16x8 vf = *(const bf16x8*)(sV + rb + (((cc << 5) + (hh << 4)) ^ sw));
        ot[dt] = MFMA32(vf, pb[cc], ot[dt]);
      }
    }
    __syncthreads();
  }
  const float linv = 1.f / lrun;
  const int b = bh / 12, h = bh - b * 12;
  u16* po = ao + ((size_t)(b*1024 + qrow)) * 768 + h*64;
#pragma unroll
  for (int dt = 0; dt < 2; ++dt) {
#pragma unroll
    for (int g = 0; g < 4; ++g) {
      ushort4 o4;
      o4.x = f2b(ot[dt][4*g + 0] * linv);
      o4.y = f2b(ot[dt][4*g + 1] * linv);
      o4.z = f2b(ot[dt][4*g + 2] * linv);
      o4.w = f2b(ot[dt][4*g + 3] * linv);
      *(ushort4*)(po + dt*32 + g*8 + hh*4) = o4;
    }
  }
}

// ---------------------------------------------------------------- proj GEMM
__global__ __launch_bounds__(256) void gemm_proj(
    const u16* __restrict__ ab, const u16* __restrict__ wb,
    const float* __restrict__ bias, float* __restrict__ out)
{
  __shared__ u16 lA[128*32];
  __shared__ u16 lB[128*32];
  const int tid = threadIdx.x;
  const int lane = tid & 63;
  const int wv = tid >> 6;
  const int wr = wv >> 1, wc = wv & 1;
  const int m0 = blockIdx.x << 7;
  const int o0 = blockIdx.y << 7;
  f32x4 acc[4][4] = {};
  const int srow = tid >> 2;
  const int sb   = (tid & 3) << 4;
  const char* gA0 = (const char*)(ab + (size_t)(m0 + srow)      * 768) + sb;
  const char* gA1 = (const char*)(ab + (size_t)(m0 + 64 + srow) * 768) + sb;
  const char* gB0 = (const char*)(wb + (size_t)(o0 + srow)      * 768) + sb;
  const char* gB1 = (const char*)(wb + (size_t)(o0 + 64 + srow) * 768) + sb;
  char* sA = (char*)lA + tid * 16;
  char* sB = (char*)lB + tid * 16;
  const int frow = lane & 15;
  const int fk   = (lane >> 4) << 4;
  for (int kt = 0; kt < 24; ++kt) {
    const int kb = kt << 6;
    gld16(gA0 + kb, sA);
    gld16(gA1 + kb, sA + 4096);
    gld16(gB0 + kb, sB);
    gld16(gB1 + kb, sB + 4096);
    asm volatile("s_waitcnt vmcnt(0)" ::: "memory");
    __syncthreads();
    bf16x8 af[4], bfr[4];
#pragma unroll
    for (int m = 0; m < 4; ++m)
      af[m] = *(const bf16x8*)((const char*)lA + ((wr*64 + m*16 + frow) << 6) + fk);
#pragma unroll
    for (int n = 0; n < 4; ++n)
      bfr[n] = *(const bf16x8*)((const char*)lB + ((wc*64 + n*16 + frow) << 6) + fk);
#pragma unroll
    for (int m = 0; m < 4; ++m)
#pragma unroll
      for (int n = 0; n < 4; ++n)
        acc[m][n] = MFMA16(af[m], bfr[n], acc[m][n]);
    __syncthreads();
  }
#pragma unroll
  for (int n = 0; n < 4; ++n) {
    const int go = o0 + wc*64 + n*16 + (lane & 15);
    const float bv = bias[go];
#pragma unroll
    for (int m = 0; m < 4; ++m) {
#pragma unroll
      for (int r = 0; r < 4; ++r) {
        const int gm = m0 + wr*64 + m*16 + ((lane >> 4) << 2) + r;
        out[(size_t)gm * 768 + go] = acc[m][n][r] + bv;
      }
    }
  }
}

// ---------------------------------------------------------------- launch
extern "C" void kernel_launch(void* const* d_in, const int* in_sizes, int n_in,
                              void* d_out, int out_size, void* d_ws, size_t ws_size,
                              hipStream_t stream)
{
  (void)in_sizes; (void)n_in; (void)out_size; (void)ws_size;
  const float* x  = (const float*)d_in[0];
  const float* wq = (const float*)d_in[1];
  const float* wp = (const float*)d_in[2];
  const float* bp = (const float*)d_in[3];
  float* out = (float*)d_out;
  char* ws = (char*)d_ws;
  u16* xb     = (u16*)(ws);              // 25,165,824  x bf16 [16384][768]
  u16* wqkvb  = (u16*)(ws + 25165824);   //  3,538,944  w_qkv bf16
  u16* wprojb = (u16*)(ws + 28704768);   //  1,179,648  w_proj bf16
  u16* qa     = (u16*)(ws + 29884416);   // 25,165,824  q  [192][1024][64] (pre-scaled)
  u16* ka     = (u16*)(ws + 55050240);   // 25,165,824  k  [192][1024][64]
  u16* vta    = (u16*)(ws + 80216064);   // 25,165,824  v^T[192][64][1024]
  u16* ao     = xb;                      // alias: xb dead after gemm_qkv

  cvt_bf16<<<2048, 256, 0, stream>>>((const float4*)x,  (ushort4*)xb,     3145728);
  cvt_bf16<<<1024, 256, 0, stream>>>((const float4*)wq, (ushort4*)wqkvb,   442368);
  cvt_bf16<<< 576, 256, 0, stream>>>((const float4*)wp, (ushort4*)wprojb,  147456);
  gemm_qkv<<<dim3(128, 18), 256, 0, stream>>>(xb, wqkvb, qa, ka, vta);
  attn_fwd<<<dim3(8, 192), 256, 0, stream>>>(qa, ka, vta, ao);
  gemm_proj<<<dim3(128, 6), 256, 0, stream>>>(ao, wprojb, bp, out);
}

// Round 3
// 236.261 us; speedup vs baseline: 1.1276x; 1.0270x over previous
//
#include <hip/hip_runtime.h>
#include <hip/hip_bf16.h>
#include <stdint.h>

typedef unsigned short u16;
typedef unsigned int   u32;
typedef short bf16x8 __attribute__((ext_vector_type(8)));
typedef float f32x4  __attribute__((ext_vector_type(4)));
typedef float f32x16 __attribute__((ext_vector_type(16)));

#define MFMA16(A,B,C) __builtin_amdgcn_mfma_f32_16x16x32_bf16((A),(B),(C),0,0,0)
#define MFMA32(A,B,C) __builtin_amdgcn_mfma_f32_32x32x16_bf16((A),(B),(C),0,0,0)

// fp32 -> bf16 round-to-nearest-even
__device__ __forceinline__ u16 f2b(float x) {
  u32 u = __float_as_uint(x);
  u += 0x7fffu + ((u >> 16) & 1u);
  return (u16)(u >> 16);
}
// packed f32 pair -> bf16x2 (hardware RNE pack)
__device__ __forceinline__ u32 cvtpk(float lo, float hi) {
  u32 r;
  asm("v_cvt_pk_bf16_f32 %0, %1, %2" : "=v"(r) : "v"(lo), "v"(hi));
  return r;
}

typedef __attribute__((address_space(1))) const void glob_void;
typedef __attribute__((address_space(3))) void lds_void;
__device__ __forceinline__ void gld16(const void* g, void* s) {
  __builtin_amdgcn_global_load_lds((glob_void*)g, (lds_void*)s, 16, 0, 0);
}

// ---------------------------------------------------------------- convert
__global__ void cvt_bf16(const float4* __restrict__ in, ushort4* __restrict__ out, int n4) {
  int stride = gridDim.x * blockDim.x;
  for (int i = blockIdx.x * blockDim.x + threadIdx.x; i < n4; i += stride) {
    float4 v = in[i];
    ushort4 o;
    o.x = f2b(v.x); o.y = f2b(v.y); o.z = f2b(v.z); o.w = f2b(v.w);
    out[i] = o;
  }
}

// ---------------------------------------------------------------- QKV GEMM
// LDS tiles are 16B-granule XOR-swizzled: physical granule = logical ^ ((row>>1)&3).
// Staging keeps LDS dest linear (gld16 constraint) and pre-swizzles the GLOBAL
// source granule; fragment reads use the per-lane-constant swizzled granule.
__global__ __launch_bounds__(256) void gemm_qkv(
    const u16* __restrict__ xb, const u16* __restrict__ wb,
    u16* __restrict__ q, u16* __restrict__ k, u16* __restrict__ vt)
{
  __shared__ u16 lA[128*32];
  __shared__ u16 lB[128*32];
  const int tid = threadIdx.x;
  const int lane = tid & 63;
  const int wv = tid >> 6;
  const int wr = wv >> 1, wc = wv & 1;
  const int m0 = blockIdx.x << 7;
  const int o0 = blockIdx.y << 7;
  f32x4 acc[4][4] = {};
  const int srow = tid >> 2;
  const int sb   = (((tid & 3) ^ ((srow >> 1) & 3)) << 4);  // pre-swizzled global granule
  const char* gA0 = (const char*)(xb + (size_t)(m0 + srow)      * 768) + sb;
  const char* gA1 = (const char*)(xb + (size_t)(m0 + 64 + srow) * 768) + sb;
  const char* gB0 = (const char*)(wb + (size_t)(o0 + srow)      * 768) + sb;
  const char* gB1 = (const char*)(wb + (size_t)(o0 + 64 + srow) * 768) + sb;
  char* sA = (char*)lA + tid * 16;
  char* sB = (char*)lB + tid * 16;
  const int frow = lane & 15;
  const int fk   = (((lane >> 4) ^ ((frow >> 1) & 3)) << 4); // swizzled read granule
  for (int kt = 0; kt < 24; ++kt) {
    const int kb = kt << 6;
    gld16(gA0 + kb, sA);
    gld16(gA1 + kb, sA + 4096);
    gld16(gB0 + kb, sB);
    gld16(gB1 + kb, sB + 4096);
    asm volatile("s_waitcnt vmcnt(0)" ::: "memory");
    __syncthreads();
    bf16x8 af[4], bfr[4];
#pragma unroll
    for (int m = 0; m < 4; ++m)
      af[m] = *(const bf16x8*)((const char*)lA + ((wr*64 + m*16 + frow) << 6) + fk);
#pragma unroll
    for (int n = 0; n < 4; ++n)
      bfr[n] = *(const bf16x8*)((const char*)lB + ((wc*64 + n*16 + frow) << 6) + fk);
#pragma unroll
    for (int m = 0; m < 4; ++m)
#pragma unroll
      for (int n = 0; n < 4; ++n)
        acc[m][n] = MFMA16(af[m], bfr[n], acc[m][n]);
    __syncthreads();
  }
  const int which = o0 / 768;
  const int ob = o0 - which * 768;
  const float QSCALE = 0.18033688011112042f; // 0.125 * log2(e)
#pragma unroll
  for (int n = 0; n < 4; ++n) {
    const int go = ob + wc*64 + n*16 + (lane & 15);
    const int h = go >> 6, d = go & 63;
#pragma unroll
    for (int m = 0; m < 4; ++m) {
      const int gm0 = m0 + wr*64 + m*16 + ((lane >> 4) << 2);
      const int b = gm0 >> 10, nn0 = gm0 & 1023;
      if (which == 2) {
        // vt[d][nn]: r varies nn consecutively -> one aligned 8B store
        ushort4 o4;
        o4.x = f2b(acc[m][n][0]); o4.y = f2b(acc[m][n][1]);
        o4.z = f2b(acc[m][n][2]); o4.w = f2b(acc[m][n][3]);
        *(ushort4*)(vt + (((size_t)((b*12 + h)*64 + d)) << 10) + nn0) = o4;
      } else if (which == 0) {
#pragma unroll
        for (int r = 0; r < 4; ++r)
          q[((size_t)((b*12 + h)*1024 + nn0 + r) << 6) + d] = f2b(acc[m][n][r] * QSCALE);
      } else {
#pragma unroll
        for (int r = 0; r < 4; ++r)
          k[((size_t)((b*12 + h)*1024 + nn0 + r) << 6) + d] = f2b(acc[m][n][r]);
      }
    }
  }
}

// ---------------------------------------------------------------- attention
// 32x32 swapped-QK structure: 4 waves x 32 q-rows = QBLK 128.
// q pre-scaled by SCALE*log2e; softmax in base 2. KVBLK=64 in LDS, rows
// XOR-swizzled (16B granules, row&7) via pre-swizzled global source.
__global__ __launch_bounds__(256) void attn_fwd(
    const u16* __restrict__ q, const u16* __restrict__ kk,
    const u16* __restrict__ vt, u16* __restrict__ ao)
{
  __shared__ u16 lK[64*64];
  __shared__ u16 lV[64*64];
  const int tid = threadIdx.x, lane = tid & 63, wv = tid >> 6;
  const int l31 = lane & 31, hh = lane >> 5;
  const int qt = blockIdx.x, bh = blockIdx.y;
  const u16*  qb = q  + ((size_t)bh << 16);
  const char* kg = (const char*)(kk + ((size_t)bh << 16));
  const char* vg = (const char*)(vt + ((size_t)bh << 16));
  const int qrow = (qt << 7) + (wv << 5) + l31;
  bf16x8 qreg[4];
#pragma unroll
  for (int c = 0; c < 4; ++c)
    qreg[c] = *(const bf16x8*)((const char*)qb + (size_t)qrow*128 + c*32 + hh*16);
  f32x16 ot[2] = {};
  float mrun = -1e30f, lrun = 0.f;
  const int o1 = tid << 4, o2 = o1 + 4096;
  const int ko1 = o1 ^ (((o1 >> 7) & 7) << 4);
  const int ko2 = o2 ^ (((o2 >> 7) & 7) << 4);
  const int d1 = o1 >> 7, d2 = o2 >> 7;
  const int vo1 = d1*2048 + ((o1 & 127) ^ ((d1 & 7) << 4));
  const int vo2 = d2*2048 + ((o2 & 127) ^ ((d2 & 7) << 4));
  char* sK = (char*)lK;
  char* sV = (char*)lV;
  for (int t0 = 0; t0 < 16; ++t0) {
    gld16(kg + (t0 << 13) + ko1, sK + o1);
    gld16(kg + (t0 << 13) + ko2, sK + o2);
    gld16(vg + (t0 << 7) + vo1, sV + o1);
    gld16(vg + (t0 << 7) + vo2, sV + o2);
    asm volatile("s_waitcnt vmcnt(0)" ::: "memory");
    __syncthreads();
    f32x16 s[2] = {};
#pragma unroll
    for (int tt = 0; tt < 2; ++tt) {
      const int row = (tt << 5) + l31;
      const int rb = row << 7;
      const int sw = (row & 7) << 4;
#pragma unroll
      for (int c = 0; c < 4; ++c) {
        bf16x8 kf = *(const bf16x8*)(sK + rb + (((c << 5) + (hh << 4)) ^ sw));
        s[tt] = MFMA32(kf, qreg[c], s[tt]);
      }
    }
    float mloc = s[0][0];
#pragma unroll
    for (int tt = 0; tt < 2; ++tt)
#pragma unroll
      for (int r = 0; r < 16; ++r) mloc = fmaxf(mloc, s[tt][r]);
    mloc = fmaxf(mloc, __shfl_xor(mloc, 32));
    const float mnew  = fmaxf(mrun, mloc);
    const float alpha = __builtin_amdgcn_exp2f(mrun - mnew);
    float sum = 0.f;
#pragma unroll
    for (int tt = 0; tt < 2; ++tt)
#pragma unroll
      for (int r = 0; r < 16; ++r) {
        s[tt][r] = __builtin_amdgcn_exp2f(s[tt][r] - mnew);
        sum += s[tt][r];
      }
    sum += __shfl_xor(sum, 32);
    lrun = lrun * alpha + sum;
    mrun = mnew;
#pragma unroll
    for (int dt = 0; dt < 2; ++dt)
#pragma unroll
      for (int r = 0; r < 16; ++r) ot[dt][r] *= alpha;
    bf16x8 pb[4];
#pragma unroll
    for (int tt = 0; tt < 2; ++tt) {
      u32 x0 = cvtpk(s[tt][0],  s[tt][1]);
      u32 y0 = cvtpk(s[tt][4],  s[tt][5]);
      u32 x1 = cvtpk(s[tt][2],  s[tt][3]);
      u32 y1 = cvtpk(s[tt][6],  s[tt][7]);
      asm("v_permlane32_swap_b32 %0, %1" : "+v"(x0), "+v"(y0));
      asm("v_permlane32_swap_b32 %0, %1" : "+v"(x1), "+v"(y1));
      u32 x2 = cvtpk(s[tt][8],  s[tt][9]);
      u32 y2 = cvtpk(s[tt][12], s[tt][13]);
      u32 x3 = cvtpk(s[tt][10], s[tt][11]);
      u32 y3 = cvtpk(s[tt][14], s[tt][15]);
      asm("v_permlane32_swap_b32 %0, %1" : "+v"(x2), "+v"(y2));
      asm("v_permlane32_swap_b32 %0, %1" : "+v"(x3), "+v"(y3));
      union { u32 u[4]; bf16x8 v; } a, b;
      a.u[0] = x0; a.u[1] = x1; a.u[2] = y0; a.u[3] = y1;
      b.u[0] = x2; b.u[1] = x3; b.u[2] = y2; b.u[3] = y3;
      pb[2*tt]     = a.v;
      pb[2*tt + 1] = b.v;
    }
#pragma unroll
    for (int dt = 0; dt < 2; ++dt) {
      const int row = (dt << 5) + l31;
      const int rb = row << 7;
      const int sw = (row & 7) << 4;
#pragma unroll
      for (int cc = 0; cc < 4; ++cc) {
        bf16x8 vf = *(const bf16x8*)(sV + rb + (((cc << 5) + (hh << 4)) ^ sw));
        ot[dt] = MFMA32(vf, pb[cc], ot[dt]);
      }
    }
    __syncthreads();
  }
  const float linv = 1.f / lrun;
  const int b = bh / 12, h = bh - b * 12;
  u16* po = ao + ((size_t)(b*1024 + qrow)) * 768 + h*64;
#pragma unroll
  for (int dt = 0; dt < 2; ++dt) {
#pragma unroll
    for (int g = 0; g < 4; ++g) {
      ushort4 o4;
      o4.x = f2b(ot[dt][4*g + 0] * linv);
      o4.y = f2b(ot[dt][4*g + 1] * linv);
      o4.z = f2b(ot[dt][4*g + 2] * linv);
      o4.w = f2b(ot[dt][4*g + 3] * linv);
      *(ushort4*)(po + dt*32 + g*8 + hh*4) = o4;
    }
  }
}

// ---------------------------------------------------------------- proj GEMM
__global__ __launch_bounds__(256) void gemm_proj(
    const u16* __restrict__ ab, const u16* __restrict__ wb,
    const float* __restrict__ bias, float* __restrict__ out)
{
  __shared__ u16 lA[128*32];
  __shared__ u16 lB[128*32];
  const int tid = threadIdx.x;
  const int lane = tid & 63;
  const int wv = tid >> 6;
  const int wr = wv >> 1, wc = wv & 1;
  const int m0 = blockIdx.x << 7;
  const int o0 = blockIdx.y << 7;
  f32x4 acc[4][4] = {};
  const int srow = tid >> 2;
  const int sb   = (((tid & 3) ^ ((srow >> 1) & 3)) << 4);
  const char* gA0 = (const char*)(ab + (size_t)(m0 + srow)      * 768) + sb;
  const char* gA1 = (const char*)(ab + (size_t)(m0 + 64 + srow) * 768) + sb;
  const char* gB0 = (const char*)(wb + (size_t)(o0 + srow)      * 768) + sb;
  const char* gB1 = (const char*)(wb + (size_t)(o0 + 64 + srow) * 768) + sb;
  char* sA = (char*)lA + tid * 16;
  char* sB = (char*)lB + tid * 16;
  const int frow = lane & 15;
  const int fk   = (((lane >> 4) ^ ((frow >> 1) & 3)) << 4);
  for (int kt = 0; kt < 24; ++kt) {
    const int kb = kt << 6;
    gld16(gA0 + kb, sA);
    gld16(gA1 + kb, sA + 4096);
    gld16(gB0 + kb, sB);
    gld16(gB1 + kb, sB + 4096);
    asm volatile("s_waitcnt vmcnt(0)" ::: "memory");
    __syncthreads();
    bf16x8 af[4], bfr[4];
#pragma unroll
    for (int m = 0; m < 4; ++m)
      af[m] = *(const bf16x8*)((const char*)lA + ((wr*64 + m*16 + frow) << 6) + fk);
#pragma unroll
    for (int n = 0; n < 4; ++n)
      bfr[n] = *(const bf16x8*)((const char*)lB + ((wc*64 + n*16 + frow) << 6) + fk);
#pragma unroll
    for (int m = 0; m < 4; ++m)
#pragma unroll
      for (int n = 0; n < 4; ++n)
        acc[m][n] = MFMA16(af[m], bfr[n], acc[m][n]);
    __syncthreads();
  }
#pragma unroll
  for (int n = 0; n < 4; ++n) {
    const int go = o0 + wc*64 + n*16 + (lane & 15);
    const float bv = bias[go];
#pragma unroll
    for (int m = 0; m < 4; ++m) {
#pragma unroll
      for (int r = 0; r < 4; ++r) {
        const int gm = m0 + wr*64 + m*16 + ((lane >> 4) << 2) + r;
        out[(size_t)gm * 768 + go] = acc[m][n][r] + bv;
      }
    }
  }
}

// ---------------------------------------------------------------- launch
extern "C" void kernel_launch(void* const* d_in, const int* in_sizes, int n_in,
                              void* d_out, int out_size, void* d_ws, size_t ws_size,
                              hipStream_t stream)
{
  (void)in_sizes; (void)n_in; (void)out_size; (void)ws_size;
  const float* x  = (const float*)d_in[0];
  const float* wq = (const float*)d_in[1];
  const float* wp = (const float*)d_in[2];
  const float* bp = (const float*)d_in[3];
  float* out = (float*)d_out;
  char* ws = (char*)d_ws;
  u16* xb     = (u16*)(ws);              // 25,165,824  x bf16 [16384][768]
  u16* wqkvb  = (u16*)(ws + 25165824);   //  3,538,944  w_qkv bf16
  u16* wprojb = (u16*)(ws + 28704768);   //  1,179,648  w_proj bf16
  u16* qa     = (u16*)(ws + 29884416);   // 25,165,824  q  [192][1024][64] (pre-scaled)
  u16* ka     = (u16*)(ws + 55050240);   // 25,165,824  k  [192][1024][64]
  u16* vta    = (u16*)(ws + 80216064);   // 25,165,824  v^T[192][64][1024]
  u16* ao     = xb;                      // alias: xb dead after gemm_qkv

  cvt_bf16<<<2048, 256, 0, stream>>>((const float4*)x,  (ushort4*)xb,     3145728);
  cvt_bf16<<<1024, 256, 0, stream>>>((const float4*)wq, (ushort4*)wqkvb,   442368);
  cvt_bf16<<< 576, 256, 0, stream>>>((const float4*)wp, (ushort4*)wprojb,  147456);
  gemm_qkv<<<dim3(128, 18), 256, 0, stream>>>(xb, wqkvb, qa, ka, vta);
  attn_fwd<<<dim3(8, 192), 256, 0, stream>>>(qa, ka, vta, ao);
  gemm_proj<<<dim3(128, 6), 256, 0, stream>>>(ao, wprojb, bp, out);
}

// Round 4
// 215.866 us; speedup vs baseline: 1.2341x; 1.0945x over previous
//
#include <hip/hip_runtime.h>
#include <hip/hip_bf16.h>
#include <stdint.h>

typedef unsigned short u16;
typedef unsigned int   u32;
typedef short bf16x8 __attribute__((ext_vector_type(8)));
typedef float f32x4  __attribute__((ext_vector_type(4)));
typedef float f32x16 __attribute__((ext_vector_type(16)));

#define MFMA16(A,B,C) __builtin_amdgcn_mfma_f32_16x16x32_bf16((A),(B),(C),0,0,0)
#define MFMA32(A,B,C) __builtin_amdgcn_mfma_f32_32x32x16_bf16((A),(B),(C),0,0,0)

// fp32 -> bf16 round-to-nearest-even
__device__ __forceinline__ u16 f2b(float x) {
  u32 u = __float_as_uint(x);
  u += 0x7fffu + ((u >> 16) & 1u);
  return (u16)(u >> 16);
}
__device__ __forceinline__ u32 cvtpk(float lo, float hi) {
  u32 r;
  asm("v_cvt_pk_bf16_f32 %0, %1, %2" : "=v"(r) : "v"(lo), "v"(hi));
  return r;
}

typedef __attribute__((address_space(1))) const void glob_void;
typedef __attribute__((address_space(3))) void lds_void;
__device__ __forceinline__ void gld16(const void* g, void* s) {
  __builtin_amdgcn_global_load_lds((glob_void*)g, (lds_void*)s, 16, 0, 0);
}

// ---------------------------------------------------------------- convert
__global__ void cvt_bf16(const float4* __restrict__ in, ushort4* __restrict__ out, int n4) {
  int stride = gridDim.x * blockDim.x;
  for (int i = blockIdx.x * blockDim.x + threadIdx.x; i < n4; i += stride) {
    float4 v = in[i];
    ushort4 o;
    o.x = f2b(v.x); o.y = f2b(v.y); o.z = f2b(v.z); o.w = f2b(v.w);
    out[i] = o;
  }
}

// ---------------------------------------------------------------- QKV GEMM
// T3-min pipeline: 2x LDS double-buffer; issue next K-step's global_load_lds
// BEFORE computing current; one counted-drain + raw s_barrier per step
// (no __syncthreads -> compiler would force-drain vmcnt before the barrier).
// LDS 16B-granule XOR-swizzle (phys = logical ^ ((row>>1)&3)), both-sides.
__global__ __launch_bounds__(256) void gemm_qkv(
    const u16* __restrict__ xb, const u16* __restrict__ wb,
    u16* __restrict__ q, u16* __restrict__ k, u16* __restrict__ vt)
{
  __shared__ u16 lA[2][128*32];
  __shared__ u16 lB[2][128*32];
  const int tid = threadIdx.x;
  const int lane = tid & 63;
  const int wv = tid >> 6;
  const int wr = wv >> 1, wc = wv & 1;
  const int m0 = blockIdx.x << 7;
  const int o0 = blockIdx.y << 7;
  f32x4 acc[4][4] = {};
  const int srow = tid >> 2;
  const int sb   = (((tid & 3) ^ ((srow >> 1) & 3)) << 4);
  const char* gA0 = (const char*)(xb + (size_t)(m0 + srow)      * 768) + sb;
  const char* gA1 = (const char*)(xb + (size_t)(m0 + 64 + srow) * 768) + sb;
  const char* gB0 = (const char*)(wb + (size_t)(o0 + srow)      * 768) + sb;
  const char* gB1 = (const char*)(wb + (size_t)(o0 + 64 + srow) * 768) + sb;
  char* sA = (char*)lA + tid * 16;
  char* sB = (char*)lB + tid * 16;
  const int frow = lane & 15;
  const int fk   = (((lane >> 4) ^ ((frow >> 1) & 3)) << 4);

#define QKV_STAGE(buf, kt) do { const int kb_ = (kt) << 6; const int bo_ = (buf) << 13; \
    gld16(gA0 + kb_, sA + bo_); gld16(gA1 + kb_, sA + bo_ + 4096); \
    gld16(gB0 + kb_, sB + bo_); gld16(gB1 + kb_, sB + bo_ + 4096); } while (0)

  QKV_STAGE(0, 0);
  asm volatile("s_waitcnt vmcnt(0) lgkmcnt(0)" ::: "memory");
  __builtin_amdgcn_s_barrier();
  for (int kt = 0; kt < 24; ++kt) {
    const int cur = kt & 1;
    if (kt < 23) QKV_STAGE(cur ^ 1, kt + 1);
    const char* bA = (const char*)lA + (cur << 13);
    const char* bB = (const char*)lB + (cur << 13);
    bf16x8 af[4], bfr[4];
#pragma unroll
    for (int m = 0; m < 4; ++m)
      af[m] = *(const bf16x8*)(bA + ((wr*64 + m*16 + frow) << 6) + fk);
#pragma unroll
    for (int n = 0; n < 4; ++n)
      bfr[n] = *(const bf16x8*)(bB + ((wc*64 + n*16 + frow) << 6) + fk);
#pragma unroll
    for (int m = 0; m < 4; ++m)
#pragma unroll
      for (int n = 0; n < 4; ++n)
        acc[m][n] = MFMA16(af[m], bfr[n], acc[m][n]);
    asm volatile("s_waitcnt vmcnt(0) lgkmcnt(0)" ::: "memory");
    __builtin_amdgcn_s_barrier();
  }
  const int which = o0 / 768;
  const int ob = o0 - which * 768;
  const float QSCALE = 0.18033688011112042f; // 0.125 * log2(e)
#pragma unroll
  for (int n = 0; n < 4; ++n) {
    const int go = ob + wc*64 + n*16 + (lane & 15);
    const int h = go >> 6, d = go & 63;
#pragma unroll
    for (int m = 0; m < 4; ++m) {
      const int gm0 = m0 + wr*64 + m*16 + ((lane >> 4) << 2);
      const int b = gm0 >> 10, nn0 = gm0 & 1023;
      if (which == 2) {
        ushort4 o4;
        o4.x = f2b(acc[m][n][0]); o4.y = f2b(acc[m][n][1]);
        o4.z = f2b(acc[m][n][2]); o4.w = f2b(acc[m][n][3]);
        *(ushort4*)(vt + (((size_t)((b*12 + h)*64 + d)) << 10) + nn0) = o4;
      } else if (which == 0) {
#pragma unroll
        for (int r = 0; r < 4; ++r)
          q[((size_t)((b*12 + h)*1024 + nn0 + r) << 6) + d] = f2b(acc[m][n][r] * QSCALE);
      } else {
#pragma unroll
        for (int r = 0; r < 4; ++r)
          k[((size_t)((b*12 + h)*1024 + nn0 + r) << 6) + d] = f2b(acc[m][n][r]);
      }
    }
  }
}

// ---------------------------------------------------------------- attention
// grid (bh=192, qt=8): flat%8 = bh%8 -> all q-tiles of one head share an XCD
// (K/V L2-resident, fetched ~once). K/V double-buffered, T3-min pipeline.
// Defer-max (T13): skip O-rescale while tile max <= running max + 8 (base-2).
__global__ __launch_bounds__(256) void attn_fwd(
    const u16* __restrict__ q, const u16* __restrict__ kk,
    const u16* __restrict__ vt, u16* __restrict__ ao)
{
  __shared__ u16 lK[2][64*64];
  __shared__ u16 lV[2][64*64];
  const int tid = threadIdx.x, lane = tid & 63, wv = tid >> 6;
  const int l31 = lane & 31, hh = lane >> 5;
  const int bh = blockIdx.x, qt = blockIdx.y;
  const u16*  qb = q  + ((size_t)bh << 16);
  const char* kg = (const char*)(kk + ((size_t)bh << 16));
  const char* vg = (const char*)(vt + ((size_t)bh << 16));
  const int qrow = (qt << 7) + (wv << 5) + l31;
  bf16x8 qreg[4];
#pragma unroll
  for (int c = 0; c < 4; ++c)
    qreg[c] = *(const bf16x8*)((const char*)qb + (size_t)qrow*128 + c*32 + hh*16);
  f32x16 ot[2] = {};
  float mrun = -1e30f, lrun = 0.f;
  const int o1 = tid << 4, o2 = o1 + 4096;
  const int ko1 = o1 ^ (((o1 >> 7) & 7) << 4);
  const int ko2 = o2 ^ (((o2 >> 7) & 7) << 4);
  const int d1 = o1 >> 7, d2 = o2 >> 7;
  const int vo1 = d1*2048 + ((o1 & 127) ^ ((d1 & 7) << 4));
  const int vo2 = d2*2048 + ((o2 & 127) ^ ((d2 & 7) << 4));
  char* sK = (char*)lK;
  char* sV = (char*)lV;

#define ATTN_STAGE(buf, t) do { const int bo_ = (buf) << 13; \
    gld16(kg + ((t) << 13) + ko1, sK + bo_ + o1); \
    gld16(kg + ((t) << 13) + ko2, sK + bo_ + o2); \
    gld16(vg + ((t) << 7) + vo1, sV + bo_ + o1); \
    gld16(vg + ((t) << 7) + vo2, sV + bo_ + o2); } while (0)

  ATTN_STAGE(0, 0);
  asm volatile("s_waitcnt vmcnt(0) lgkmcnt(0)" ::: "memory");
  __builtin_amdgcn_s_barrier();
  for (int t0 = 0; t0 < 16; ++t0) {
    const int cur = t0 & 1;
    if (t0 < 15) ATTN_STAGE(cur ^ 1, t0 + 1);
    const char* bK = (const char*)lK + (cur << 13);
    const char* bV = (const char*)lV + (cur << 13);
    f32x16 s[2] = {};
#pragma unroll
    for (int tt = 0; tt < 2; ++tt) {
      const int row = (tt << 5) + l31;
      const int rb = row << 7;
      const int sw = (row & 7) << 4;
#pragma unroll
      for (int c = 0; c < 4; ++c) {
        bf16x8 kf = *(const bf16x8*)(bK + rb + (((c << 5) + (hh << 4)) ^ sw));
        s[tt] = MFMA32(kf, qreg[c], s[tt]);
      }
    }
    float mloc = s[0][0];
#pragma unroll
    for (int tt = 0; tt < 2; ++tt)
#pragma unroll
      for (int r = 0; r < 16; ++r) mloc = fmaxf(mloc, s[tt][r]);
    if (!__all(mloc <= mrun + 8.f)) {
      mloc = fmaxf(mloc, __shfl_xor(mloc, 32));
      const float mnew  = fmaxf(mrun, mloc);
      const float alpha = __builtin_amdgcn_exp2f(mrun - mnew);
      lrun *= alpha;
#pragma unroll
      for (int dt = 0; dt < 2; ++dt)
#pragma unroll
        for (int r = 0; r < 16; ++r) ot[dt][r] *= alpha;
      mrun = mnew;
    }
    float sum = 0.f;
#pragma unroll
    for (int tt = 0; tt < 2; ++tt)
#pragma unroll
      for (int r = 0; r < 16; ++r) {
        s[tt][r] = __builtin_amdgcn_exp2f(s[tt][r] - mrun);
        sum += s[tt][r];
      }
    sum += __shfl_xor(sum, 32);
    lrun += sum;
    bf16x8 pb[4];
#pragma unroll
    for (int tt = 0; tt < 2; ++tt) {
      u32 x0 = cvtpk(s[tt][0],  s[tt][1]);
      u32 y0 = cvtpk(s[tt][4],  s[tt][5]);
      u32 x1 = cvtpk(s[tt][2],  s[tt][3]);
      u32 y1 = cvtpk(s[tt][6],  s[tt][7]);
      asm("v_permlane32_swap_b32 %0, %1" : "+v"(x0), "+v"(y0));
      asm("v_permlane32_swap_b32 %0, %1" : "+v"(x1), "+v"(y1));
      u32 x2 = cvtpk(s[tt][8],  s[tt][9]);
      u32 y2 = cvtpk(s[tt][12], s[tt][13]);
      u32 x3 = cvtpk(s[tt][10], s[tt][11]);
      u32 y3 = cvtpk(s[tt][14], s[tt][15]);
      asm("v_permlane32_swap_b32 %0, %1" : "+v"(x2), "+v"(y2));
      asm("v_permlane32_swap_b32 %0, %1" : "+v"(x3), "+v"(y3));
      union { u32 u[4]; bf16x8 v; } a, b;
      a.u[0] = x0; a.u[1] = x1; a.u[2] = y0; a.u[3] = y1;
      b.u[0] = x2; b.u[1] = x3; b.u[2] = y2; b.u[3] = y3;
      pb[2*tt]     = a.v;
      pb[2*tt + 1] = b.v;
    }
#pragma unroll
    for (int dt = 0; dt < 2; ++dt) {
      const int row = (dt << 5) + l31;
      const int rb = row << 7;
      const int sw = (row & 7) << 4;
#pragma unroll
      for (int cc = 0; cc < 4; ++cc) {
        bf16x8 vf = *(const bf16x8*)(bV + rb + (((cc << 5) + (hh << 4)) ^ sw));
        ot[dt] = MFMA32(vf, pb[cc], ot[dt]);
      }
    }
    asm volatile("s_waitcnt vmcnt(0) lgkmcnt(0)" ::: "memory");
    __builtin_amdgcn_s_barrier();
  }
  const float linv = 1.f / lrun;
  const int b = bh / 12, h = bh - b * 12;
  u16* po = ao + ((size_t)(b*1024 + qrow)) * 768 + h*64;
#pragma unroll
  for (int dt = 0; dt < 2; ++dt) {
#pragma unroll
    for (int g = 0; g < 4; ++g) {
      ushort4 o4;
      o4.x = f2b(ot[dt][4*g + 0] * linv);
      o4.y = f2b(ot[dt][4*g + 1] * linv);
      o4.z = f2b(ot[dt][4*g + 2] * linv);
      o4.w = f2b(ot[dt][4*g + 3] * linv);
      *(ushort4*)(po + dt*32 + g*8 + hh*4) = o4;
    }
  }
}

// ---------------------------------------------------------------- proj GEMM
__global__ __launch_bounds__(256) void gemm_proj(
    const u16* __restrict__ ab, const u16* __restrict__ wb,
    const float* __restrict__ bias, float* __restrict__ out)
{
  __shared__ u16 lA[2][128*32];
  __shared__ u16 lB[2][128*32];
  const int tid = threadIdx.x;
  const int lane = tid & 63;
  const int wv = tid >> 6;
  const int wr = wv >> 1, wc = wv & 1;
  const int m0 = blockIdx.x << 7;
  const int o0 = blockIdx.y << 7;
  f32x4 acc[4][4] = {};
  const int srow = tid >> 2;
  const int sb   = (((tid & 3) ^ ((srow >> 1) & 3)) << 4);
  const char* gA0 = (const char*)(ab + (size_t)(m0 + srow)      * 768) + sb;
  const char* gA1 = (const char*)(ab + (size_t)(m0 + 64 + srow) * 768) + sb;
  const char* gB0 = (const char*)(wb + (size_t)(o0 + srow)      * 768) + sb;
  const char* gB1 = (const char*)(wb + (size_t)(o0 + 64 + srow) * 768) + sb;
  char* sA = (char*)lA + tid * 16;
  char* sB = (char*)lB + tid * 16;
  const int frow = lane & 15;
  const int fk   = (((lane >> 4) ^ ((frow >> 1) & 3)) << 4);

  QKV_STAGE(0, 0);
  asm volatile("s_waitcnt vmcnt(0) lgkmcnt(0)" ::: "memory");
  __builtin_amdgcn_s_barrier();
  for (int kt = 0; kt < 24; ++kt) {
    const int cur = kt & 1;
    if (kt < 23) QKV_STAGE(cur ^ 1, kt + 1);
    const char* bA = (const char*)lA + (cur << 13);
    const char* bB = (const char*)lB + (cur << 13);
    bf16x8 af[4], bfr[4];
#pragma unroll
    for (int m = 0; m < 4; ++m)
      af[m] = *(const bf16x8*)(bA + ((wr*64 + m*16 + frow) << 6) + fk);
#pragma unroll
    for (int n = 0; n < 4; ++n)
      bfr[n] = *(const bf16x8*)(bB + ((wc*64 + n*16 + frow) << 6) + fk);
#pragma unroll
    for (int m = 0; m < 4; ++m)
#pragma unroll
      for (int n = 0; n < 4; ++n)
        acc[m][n] = MFMA16(af[m], bfr[n], acc[m][n]);
    asm volatile("s_waitcnt vmcnt(0) lgkmcnt(0)" ::: "memory");
    __builtin_amdgcn_s_barrier();
  }
#pragma unroll
  for (int n = 0; n < 4; ++n) {
    const int go = o0 + wc*64 + n*16 + (lane & 15);
    const float bv = bias[go];
#pragma unroll
    for (int m = 0; m < 4; ++m) {
#pragma unroll
      for (int r = 0; r < 4; ++r) {
        const int gm = m0 + wr*64 + m*16 + ((lane >> 4) << 2) + r;
        out[(size_t)gm * 768 + go] = acc[m][n][r] + bv;
      }
    }
  }
}

// ---------------------------------------------------------------- launch
extern "C" void kernel_launch(void* const* d_in, const int* in_sizes, int n_in,
                              void* d_out, int out_size, void* d_ws, size_t ws_size,
                              hipStream_t stream)
{
  (void)in_sizes; (void)n_in; (void)out_size; (void)ws_size;
  const float* x  = (const float*)d_in[0];
  const float* wq = (const float*)d_in[1];
  const float* wp = (const float*)d_in[2];
  const float* bp = (const float*)d_in[3];
  float* out = (float*)d_out;
  char* ws = (char*)d_ws;
  u16* xb     = (u16*)(ws);              // 25,165,824  x bf16 [16384][768]
  u16* wqkvb  = (u16*)(ws + 25165824);   //  3,538,944  w_qkv bf16
  u16* wprojb = (u16*)(ws + 28704768);   //  1,179,648  w_proj bf16
  u16* qa     = (u16*)(ws + 29884416);   // 25,165,824  q  [192][1024][64] (pre-scaled)
  u16* ka     = (u16*)(ws + 55050240);   // 25,165,824  k  [192][1024][64]
  u16* vta    = (u16*)(ws + 80216064);   // 25,165,824  v^T[192][64][1024]
  u16* ao     = xb;                      // alias: xb dead after gemm_qkv

  cvt_bf16<<<2048, 256, 0, stream>>>((const float4*)x,  (ushort4*)xb,     3145728);
  cvt_bf16<<<1024, 256, 0, stream>>>((const float4*)wq, (ushort4*)wqkvb,   442368);
  cvt_bf16<<< 576, 256, 0, stream>>>((const float4*)wp, (ushort4*)wprojb,  147456);
  gemm_qkv<<<dim3(128, 18), 256, 0, stream>>>(xb, wqkvb, qa, ka, vta);
  attn_fwd<<<dim3(192, 8), 256, 0, stream>>>(qa, ka, vta, ao);
  gemm_proj<<<dim3(128, 6), 256, 0, stream>>>(ao, wprojb, bp, out);
}